// Round 12
// baseline (232.920 us; speedup 1.0000x reference)
//
#include <hip/hip_runtime.h>

typedef unsigned short ushort_t;
typedef unsigned int uint_t;
typedef __attribute__((ext_vector_type(4))) float f32x4;
typedef __attribute__((ext_vector_type(2))) float f32x2;
typedef __attribute__((ext_vector_type(8))) short s16x8;
typedef __attribute__((ext_vector_type(8))) _Float16 f16x8;
typedef __attribute__((ext_vector_type(4))) unsigned short u16x4;

#define NEGV -60000.0f

// Session lessons (R7-R10, keep for future edits):
//  - launch_bounds below accumulator footprint -> scratch spill (R7: 4.4x).
//  - atomic mean-fusion at 32-way contention -> serialization (R8: +29us).
//  - 2-byte scattered epilogue stores (fused V^T) -> write-path bound (R9).
//  - inlining the bf16 cvt into the latency-bound GEMM -> conflicts+VALU on
//    critical path beat the ~15us separate BW-bound pass (R10: -24us).
//  - GEMM inner-schedule plateau: 62-66us across 5 schedules at K=512/1024
//    (2ph-128^2, ring3, 8ph/4ph-256^2, BK=32) - short-K latency-bound.

__device__ __forceinline__ ushort_t f2bf(float f) {
  unsigned int u = __builtin_bit_cast(unsigned int, f);
  return (ushort_t)((u + 0x7fffu + ((u >> 16) & 1u)) >> 16);
}
__device__ __forceinline__ float bf2f(ushort_t h) {
  unsigned int u = ((unsigned int)h) << 16;
  return __builtin_bit_cast(float, u);
}
__device__ __forceinline__ void gload_lds16(const void* g, void* l) {
  __builtin_amdgcn_global_load_lds(
      (const __attribute__((address_space(1))) unsigned int*)g,
      (__attribute__((address_space(3))) unsigned int*)l, 16, 0, 0);
}

// ---------------------------------------------------------------------------
// 128x128 2-phase MFMA GEMM (R2 structure).  Used for QKV (EPI=4, with
// per-panel length skip) and for FFN2 single-K (EPI=0: M=16384 N=512 K=2048,
// grid (4,128) = 512 blocks = 2/CU — the un-split shape the 256^2 tile can't
// reach; removes 32MB H2 write + 32MB ln2 read vs split-K=2).
// Skip rules (EPI=4; panel rows [s0,s0+128) of batch b, s0=m0&511):
//  z=0 (Q): skip iff QL<=s0; z=1 (K): skip iff KL<=s0;
//  z=2 (V): skip iff KL<=s0 && KL!=1 (KL==1 -> uniform softmax reads all V).
// ---------------------------------------------------------------------------
template<int EPI>
__global__ __launch_bounds__(256)
void gemm_bt(const ushort_t* __restrict__ A, const ushort_t* __restrict__ A2,
             int lda,
             const ushort_t* __restrict__ Bt, int ldb,
             void* __restrict__ Cv, int ldc, int K,
             long long sB, long long sC,
             const int* __restrict__ qlen, const int* __restrict__ klen)
{
  __shared__ ushort_t As[2][128 * 32];
  __shared__ ushort_t Bs[2][128 * 32];

  const int tid = threadIdx.x;
  const int w = tid >> 6;
  const int lane = tid & 63;
  const int z = blockIdx.z;

  const ushort_t* Az = (z == 0) ? A : A2;
  const ushort_t* Bz = Bt + (size_t)z * sB;

  const int orig = blockIdx.x + gridDim.x * blockIdx.y;
  const int bx = (orig >> 3) % gridDim.x;
  const int by = (orig & 7) + 8 * ((orig >> 3) / gridDim.x);
  const int m0 = by * 128;
  const int n0 = bx * 128;

  if constexpr (EPI == 4) {
    const int s0 = m0 & 511;
    if (s0) {
      const int b = m0 >> 9;
      const int L = (z == 0) ? qlen[b] : klen[b];
      if (L <= s0 && !(z == 2 && L == 1)) return;  // panel never read downstream
    }
  }

  const int wm = (w >> 1) * 64;
  const int wn = (w & 1) * 64;

  f32x4 acc[4][4];
#pragma unroll
  for (int m = 0; m < 4; ++m)
#pragma unroll
    for (int n = 0; n < 4; ++n)
      acc[m][n] = (f32x4){0.f, 0.f, 0.f, 0.f};

  const int cA0 = w * 64 + lane;   // 16B chunk id: row*4 + kc
  const int cA1 = 256 + cA0;
  const int rA0 = cA0 >> 2, kO0 = (cA0 & 3) * 8;
  const int rA1 = cA1 >> 2, kO1 = (cA1 & 3) * 8;

  auto stage = [&](int p, int k0) {
    gload_lds16(Az + (size_t)(m0 + rA0) * lda + (k0 + kO0),
                As[p] + (size_t)(w * 64) * 8);
    gload_lds16(Az + (size_t)(m0 + rA1) * lda + (k0 + kO1),
                As[p] + (size_t)(256 + w * 64) * 8);
    gload_lds16(Bz + (size_t)(n0 + rA0) * ldb + (k0 + kO0),
                Bs[p] + (size_t)(w * 64) * 8);
    gload_lds16(Bz + (size_t)(n0 + rA1) * ldb + (k0 + kO1),
                Bs[p] + (size_t)(256 + w * 64) * 8);
  };

  const int nk = K >> 5;
  stage(0, 0);
  __syncthreads();
  for (int kt = 0; kt < nk; ++kt) {
    const int p = kt & 1;
    if (kt + 1 < nk) stage(p ^ 1, (kt + 1) << 5);  // prefetch next tile

    s16x8 af[4], bfr[4];
#pragma unroll
    for (int m = 0; m < 4; ++m)
      af[m] = *(const s16x8*)(As[p] + (size_t)(wm + m * 16 + (lane & 15)) * 32 +
                              ((lane >> 4) * 8));
#pragma unroll
    for (int n = 0; n < 4; ++n)
      bfr[n] = *(const s16x8*)(Bs[p] + (size_t)(wn + n * 16 + (lane & 15)) * 32 +
                               ((lane >> 4) * 8));
#pragma unroll
    for (int m = 0; m < 4; ++m)
#pragma unroll
      for (int n = 0; n < 4; ++n)
        acc[m][n] = __builtin_amdgcn_mfma_f32_16x16x32_bf16(af[m], bfr[n],
                                                            acc[m][n], 0, 0, 0);
    __syncthreads();
  }

  const float s0v = (EPI == 4 && z == 0) ? 0.125f : 1.0f;
  char* Cz = (char*)Cv + (size_t)sC * z;
  const int r_base = (lane >> 4) * 4;
  const int c_base = lane & 15;
#pragma unroll
  for (int m = 0; m < 4; ++m)
#pragma unroll
    for (int n = 0; n < 4; ++n)
#pragma unroll
      for (int j = 0; j < 4; ++j) {
        const int rg = m0 + wm + m * 16 + r_base + j;
        const int cg = n0 + wn + n * 16 + c_base;
        float v = acc[m][n][j];
        const size_t idx = (size_t)rg * ldc + cg;
        if constexpr (EPI == 0) {
          ((float*)Cz)[idx] = v;
        } else if constexpr (EPI == 2) {
          ((ushort_t*)Cz)[idx] = f2bf(fmaxf(v, 0.f));
        } else {
          ((ushort_t*)Cz)[idx] = f2bf(v * s0v);
        }
      }
}

// ---------------------------------------------------------------------------
// 256x256 4-phase MFMA GEMM (BK=64, 128KB LDS, (512,2)) — FFN1.
// ---------------------------------------------------------------------------
template<int EPI>
__global__ __launch_bounds__(512, 2)
void gemm256(const ushort_t* __restrict__ A, const ushort_t* __restrict__ A2,
             int lda,
             const ushort_t* __restrict__ Bt, int ldb,
             void* __restrict__ Cv, int ldc, int K,
             long long sB, long long sC)
{
  __shared__ ushort_t Asm[2][16384];   // [buf][256 rows x 64 cols]
  __shared__ ushort_t Bsm[2][16384];

  const int tid = threadIdx.x, wid = tid >> 6, lane = tid & 63;
  const int wr = wid >> 2, wc = wid & 3;       // 2 x 4 wave grid
  const int fr = lane & 15, fq = lane >> 4;
  const int z = blockIdx.z;

  const ushort_t* Az = (z == 0) ? A : A2;
  const ushort_t* Bz = Bt + (size_t)z * sB;

  const int orig = blockIdx.x + gridDim.x * blockIdx.y;
  const int bx = (orig >> 3) % gridDim.x;
  const int by = (orig & 7) + 8 * ((orig >> 3) / gridDim.x);
  const int m0 = by * 256, n0 = bx * 256;

  const int rr0 = tid >> 3;                          // 0..63 (second is +64)
  const int ks = (((tid & 7) ^ (rr0 & 7)) * 8);      // (rr+64)&7 == rr&7

  auto stageA = [&](int p, int kt, int h) {
    const ushort_t* s = Az + (size_t)(m0 + h * 128 + rr0) * lda + kt * 64 + ks;
    ushort_t* d = &Asm[p][h * 8192 + tid * 8];
    gload_lds16(s, d);
    gload_lds16(s + (size_t)64 * lda, d + 4096);
  };
  auto stageB = [&](int p, int kt, int h) {
    const ushort_t* s = Bz + (size_t)(n0 + h * 128 + rr0) * ldb + kt * 64 + ks;
    ushort_t* d = &Bsm[p][h * 8192 + tid * 8];
    gload_lds16(s, d);
    gload_lds16(s + (size_t)64 * ldb, d + 4096);
  };
  auto ldA = [&](int p, int mi, int kc) -> s16x8 {
    const int R = wr * 128 + mi * 16 + fr;
    return *(const s16x8*)(&Asm[p][R * 64 + (((kc * 4 + fq) ^ (fr & 7)) * 8)]);
  };
  auto ldB = [&](int p, int ni, int kc) -> s16x8 {
    const int R = wc * 64 + ni * 16 + fr;
    return *(const s16x8*)(&Bsm[p][R * 64 + (((kc * 4 + fq) ^ (fr & 7)) * 8)]);
  };

  f32x4 acc[8][4];
#pragma unroll
  for (int m = 0; m < 8; ++m)
#pragma unroll
    for (int n = 0; n < 4; ++n)
      acc[m][n] = (f32x4){0.f, 0.f, 0.f, 0.f};

  const int nk = K >> 6;
  const int niter = nk >> 1;

  stageB(0, 0, 0); stageB(0, 0, 1);
  stageA(0, 0, 0); stageA(0, 0, 1);
  stageA(1, 1, 0); stageA(1, 1, 1);
  stageB(1, 1, 0); stageB(1, 1, 1);
  asm volatile("s_waitcnt vmcnt(8)" ::: "memory");   // tile0 landed
  __builtin_amdgcn_s_barrier();

  s16x8 af[4][2], bf[4][2];

  for (int it = 0; it < niter; ++it) {
    const int T = 2 * it;
    const bool more = (it + 1 < niter);

    // ---- phase A: tile T (buf0), acc rows 0-3 ----
#pragma unroll
    for (int mi = 0; mi < 4; ++mi)
#pragma unroll
      for (int kc = 0; kc < 2; ++kc) af[mi][kc] = ldA(0, mi, kc);
#pragma unroll
    for (int ni = 0; ni < 4; ++ni)
#pragma unroll
      for (int kc = 0; kc < 2; ++kc) bf[ni][kc] = ldB(0, ni, kc);
    if (it) { stageA(1, T + 1, 0); stageA(1, T + 1, 1); }
    __builtin_amdgcn_s_barrier();
    asm volatile("s_waitcnt lgkmcnt(0)" ::: "memory");
    __builtin_amdgcn_s_setprio(1);
#pragma unroll
    for (int mi = 0; mi < 4; ++mi)
#pragma unroll
      for (int ni = 0; ni < 4; ++ni)
#pragma unroll
        for (int kc = 0; kc < 2; ++kc)
          acc[mi][ni] = __builtin_amdgcn_mfma_f32_16x16x32_bf16(
              af[mi][kc], bf[ni][kc], acc[mi][ni], 0, 0, 0);
    __builtin_amdgcn_s_setprio(0);
    __builtin_amdgcn_s_barrier();

    // ---- phase B: tile T, acc rows 4-7 ----
#pragma unroll
    for (int mi = 0; mi < 4; ++mi)
#pragma unroll
      for (int kc = 0; kc < 2; ++kc) af[mi][kc] = ldA(0, 4 + mi, kc);
    if (more) {
      stageB(0, T + 2, 0); stageB(0, T + 2, 1);
      asm volatile("s_waitcnt vmcnt(4)" ::: "memory");  // tile T+1 landed
    } else {
      asm volatile("s_waitcnt vmcnt(0)" ::: "memory");
    }
    __builtin_amdgcn_s_barrier();
    asm volatile("s_waitcnt lgkmcnt(0)" ::: "memory");
    __builtin_amdgcn_s_setprio(1);
#pragma unroll
    for (int mi = 0; mi < 4; ++mi)
#pragma unroll
      for (int ni = 0; ni < 4; ++ni)
#pragma unroll
        for (int kc = 0; kc < 2; ++kc)
          acc[4 + mi][ni] = __builtin_amdgcn_mfma_f32_16x16x32_bf16(
              af[mi][kc], bf[ni][kc], acc[4 + mi][ni], 0, 0, 0);
    __builtin_amdgcn_s_setprio(0);
    __builtin_amdgcn_s_barrier();

    // ---- phase C: tile T+1 (buf1), acc rows 0-3 ----
#pragma unroll
    for (int mi = 0; mi < 4; ++mi)
#pragma unroll
      for (int kc = 0; kc < 2; ++kc) af[mi][kc] = ldA(1, mi, kc);
#pragma unroll
    for (int ni = 0; ni < 4; ++ni)
#pragma unroll
      for (int kc = 0; kc < 2; ++kc) bf[ni][kc] = ldB(1, ni, kc);
    if (more) { stageA(0, T + 2, 0); stageA(0, T + 2, 1); }
    __builtin_amdgcn_s_barrier();
    asm volatile("s_waitcnt lgkmcnt(0)" ::: "memory");
    __builtin_amdgcn_s_setprio(1);
#pragma unroll
    for (int mi = 0; mi < 4; ++mi)
#pragma unroll
      for (int ni = 0; ni < 4; ++ni)
#pragma unroll
        for (int kc = 0; kc < 2; ++kc)
          acc[mi][ni] = __builtin_amdgcn_mfma_f32_16x16x32_bf16(
              af[mi][kc], bf[ni][kc], acc[mi][ni], 0, 0, 0);
    __builtin_amdgcn_s_setprio(0);
    __builtin_amdgcn_s_barrier();

    // ---- phase D: tile T+1, acc rows 4-7 ----
#pragma unroll
    for (int mi = 0; mi < 4; ++mi)
#pragma unroll
      for (int kc = 0; kc < 2; ++kc) af[mi][kc] = ldA(1, 4 + mi, kc);
    if (more) {
      stageB(1, T + 3, 0); stageB(1, T + 3, 1);
      asm volatile("s_waitcnt vmcnt(4)" ::: "memory");  // tile T+2 landed
    } else {
      asm volatile("s_waitcnt vmcnt(0)" ::: "memory");
    }
    __builtin_amdgcn_s_barrier();
    asm volatile("s_waitcnt lgkmcnt(0)" ::: "memory");
    __builtin_amdgcn_s_setprio(1);
#pragma unroll
    for (int mi = 0; mi < 4; ++mi)
#pragma unroll
      for (int ni = 0; ni < 4; ++ni)
#pragma unroll
        for (int kc = 0; kc < 2; ++kc)
          acc[4 + mi][ni] = __builtin_amdgcn_mfma_f32_16x16x32_bf16(
              af[mi][kc], bf[ni][kc], acc[4 + mi][ni], 0, 0, 0);
    __builtin_amdgcn_s_setprio(0);
    __builtin_amdgcn_s_barrier();
  }

  // epilogue
  const float s0 = (EPI == 4 && z == 0) ? 0.125f : 1.0f;
  char* Cz = (char*)Cv + (size_t)sC * z;
  const int rb = fq * 4;
#pragma unroll
  for (int mi = 0; mi < 8; ++mi)
#pragma unroll
    for (int ni = 0; ni < 4; ++ni)
#pragma unroll
      for (int j = 0; j < 4; ++j) {
        const int rg = m0 + wr * 128 + mi * 16 + rb + j;
        const int cg = n0 + wc * 64 + ni * 16 + fr;
        float v = acc[mi][ni][j];
        const size_t idx = (size_t)rg * ldc + cg;
        if constexpr (EPI == 0) {
          ((float*)Cz)[idx] = v;
        } else if constexpr (EPI == 2) {
          ((ushort_t*)Cz)[idx] = f2bf(fmaxf(v, 0.f));
        } else {
          ((ushort_t*)Cz)[idx] = f2bf(v * s0);
        }
      }
}

// ---------------------------------------------------------------------------
// Fused preprocessing: one dispatch replaces 2x cvt_bf16 + 5x transpose_cvt.
// ---------------------------------------------------------------------------
__global__ __launch_bounds__(256)
void prep(const float* __restrict__ q, const float* __restrict__ k,
          ushort_t* __restrict__ XQ, ushort_t* __restrict__ XK,
          const float* __restrict__ W_Q, const float* __restrict__ W_K,
          const float* __restrict__ W_V,
          const float* __restrict__ fw1, const float* __restrict__ fw2,
          ushort_t* __restrict__ WQT, ushort_t* __restrict__ FW1T,
          ushort_t* __restrict__ FW2T)
{
  __shared__ float tile[32][33];
  int bid = blockIdx.x;
  if (bid < 16384) {
    const float* in = (bid < 8192) ? q : k;
    ushort_t* outp = (bid < 8192) ? XQ : XK;
    int i = (bid & 8191) * 256 + threadIdx.x;
    f32x4 v = ((const f32x4*)in)[i];
    u16x4 o;
#pragma unroll
    for (int j = 0; j < 4; ++j) o[j] = f2bf(v[j]);
    ((u16x4*)outp)[i] = o;
    return;
  }
  bid -= 16384;
  const float* in;
  ushort_t* outp;
  int R, C, bx, by;
  if (bid < 768) {
    int zz = bid >> 8, idx = bid & 255;
    in = (zz == 0) ? W_Q : (zz == 1) ? W_K : W_V;
    outp = WQT + zz * 262144;
    R = 512; C = 512; bx = idx & 15; by = idx >> 4;
  } else if (bid < 1792) {
    int idx = bid - 768;
    in = fw1; outp = FW1T; R = 512; C = 2048; bx = idx & 63; by = idx >> 6;
  } else {
    int idx = bid - 1792;
    in = fw2; outp = FW2T; R = 2048; C = 512; bx = idx & 15; by = idx >> 4;
  }
  const int c0 = bx * 32, r0 = by * 32;
  const int tx = threadIdx.x & 31, ty = threadIdx.x >> 5;
#pragma unroll
  for (int i = 0; i < 32; i += 8)
    tile[ty + i][tx] = in[(size_t)(r0 + ty + i) * C + (c0 + tx)];
  __syncthreads();
#pragma unroll
  for (int i = 0; i < 32; i += 8)
    outp[(size_t)(c0 + ty + i) * R + (r0 + tx)] = f2bf(tile[tx][ty + i]);
}

// ---------------------------------------------------------------------------
// Flash attention: block = (b, h, 64-q-tile); 4 waves x 16 q-rows.
// ---------------------------------------------------------------------------
__global__ __launch_bounds__(256, 4)
void flash_attn(const ushort_t* __restrict__ Qg, const ushort_t* __restrict__ Kg,
                const ushort_t* __restrict__ Vt, ushort_t* __restrict__ AOb,
                const int* __restrict__ qlen, const int* __restrict__ klen)
{
  __shared__ ushort_t sm[20480];  // buf0(8K K + 8K V B) | buf1 | PQ(8KB)
  ushort_t* PQ = sm + 16384;

  const int tid = threadIdx.x, w = tid >> 6, lane = tid & 63;
  const int fr = lane & 15, fq = lane >> 4;

  int id = blockIdx.x;
  id = (id & 7) * 256 + (id >> 3);           // XCD swizzle (2048 blocks)
  const int qt = id & 7, h = (id >> 3) & 7, b = id >> 6;
  const int q0 = qt * 64;
  const int KL = klen[b], QL = qlen[b];

  if (q0 >= QL) {
#pragma unroll
    for (int i = 0; i < 4; ++i) {
      int idx = i * 256 + tid;
      int rr = idx >> 4, cc = (idx & 15) << 2;
      *(u16x4*)&AOb[((size_t)(b * 512 + q0 + rr)) * 512 + h * 64 + cc] =
          (u16x4){0, 0, 0, 0};
    }
    return;
  }

  int nt = (KL + 63) >> 6;                   // KV tiles actually needed
  if (KL == 1) nt = 8;                       // degenerate: uniform over 512

  const ushort_t* Qrow = Qg + ((size_t)(b * 512 + q0)) * 512 + h * 64;
  const ushort_t* Krow = Kg + ((size_t)b * 512) * 512 + h * 64;
  const ushort_t* Vrow = Vt + (((size_t)b * 8 + h) * 64) * 512;

#pragma unroll
  for (int i = 0; i < 2; ++i) {
    int s = i * 256 + tid, r = s >> 3, c = (s & 7) ^ (r & 7);
    gload_lds16(Qrow + (size_t)r * 512 + c * 8, PQ + (i * 256 + w * 64) * 8);
  }
#pragma unroll
  for (int i = 0; i < 2; ++i) {
    int s = i * 256 + tid, r = s >> 3, c = (s & 7) ^ (r & 7);
    gload_lds16(Krow + (size_t)r * 512 + c * 8, sm + (i * 256 + w * 64) * 8);
    gload_lds16(Vrow + (size_t)r * 512 + c * 8, sm + 4096 + (i * 256 + w * 64) * 8);
  }
  __syncthreads();

  s16x8 qf[2];
#pragma unroll
  for (int kc = 0; kc < 2; ++kc) {
    int r = w * 16 + fr;
    qf[kc] = *(const s16x8*)(PQ + r * 64 + (((kc * 4 + fq) ^ (r & 7)) * 8));
  }

  float mrun[4], lrun[4];
  f32x4 oacc[4];
#pragma unroll
  for (int j = 0; j < 4; ++j) { mrun[j] = -1e30f; lrun[j] = 0.f; }
#pragma unroll
  for (int nd = 0; nd < 4; ++nd) oacc[nd] = (f32x4){0.f, 0.f, 0.f, 0.f};

  for (int t = 0; t < nt; ++t) {
    ushort_t* Kb = sm + (t & 1) * 8192;
    ushort_t* Vb = Kb + 4096;
    if (t + 1 < nt) {
      const int kv1 = (t + 1) * 64;
      ushort_t* Kn = sm + ((t + 1) & 1) * 8192;
#pragma unroll
      for (int i = 0; i < 2; ++i) {
        int s = i * 256 + tid, r = s >> 3, c = (s & 7) ^ (r & 7);
        gload_lds16(Krow + (size_t)(kv1 + r) * 512 + c * 8,
                    Kn + (i * 256 + w * 64) * 8);
        gload_lds16(Vrow + (size_t)r * 512 + kv1 + c * 8,
                    Kn + 4096 + (i * 256 + w * 64) * 8);
      }
    }
    const int kv0 = t * 64;

    f32x4 sacc[4];
#pragma unroll
    for (int n = 0; n < 4; ++n) sacc[n] = (f32x4){0.f, 0.f, 0.f, 0.f};
#pragma unroll
    for (int n = 0; n < 4; ++n)
#pragma unroll
      for (int kc = 0; kc < 2; ++kc) {
        int r = n * 16 + fr;
        s16x8 kf = *(const s16x8*)(Kb + r * 64 + (((kc * 4 + fq) ^ (r & 7)) * 8));
        sacc[n] = __builtin_amdgcn_mfma_f32_16x16x32_bf16(qf[kc], kf, sacc[n], 0, 0, 0);
      }

#pragma unroll
    for (int j = 0; j < 4; ++j) {
      const int rl = w * 16 + fq * 4 + j;
      const int rg = q0 + rl;
      float sv[4];
      float tmax = -1e30f;
#pragma unroll
      for (int n = 0; n < 4; ++n) {
        int cg = kv0 + n * 16 + fr;
        float v = sacc[n][j];
        if (cg >= KL || cg == rg) v = NEGV;
        sv[n] = v;
        tmax = fmaxf(tmax, v);
      }
#pragma unroll
      for (int o = 1; o < 16; o <<= 1) tmax = fmaxf(tmax, __shfl_xor(tmax, o));
      const float mnew = fmaxf(mrun[j], tmax);
      const float sf = __expf(mrun[j] - mnew);
      mrun[j] = mnew;
      float ps = 0.f;
      _Float16* prow = (_Float16*)(PQ + rl * 64);
#pragma unroll
      for (int n = 0; n < 4; ++n) {
        float p = __expf(sv[n] - mnew);
        ps += p;
        int cl = n * 2 + (fr >> 3);
        prow[((cl ^ (rl & 7)) * 8) + (fr & 7)] = (_Float16)p;
      }
      lrun[j] = lrun[j] * sf + ps;
#pragma unroll
      for (int nd = 0; nd < 4; ++nd) oacc[nd][j] *= sf;
    }

#pragma unroll
    for (int kc = 0; kc < 2; ++kc) {
      const int rl = w * 16 + fr;
      s16x8 pf = *(const s16x8*)(PQ + rl * 64 + (((kc * 4 + fq) ^ (rl & 7)) * 8));
#pragma unroll
      for (int nd = 0; nd < 4; ++nd) {
        int d = nd * 16 + fr;
        s16x8 vf = *(const s16x8*)(Vb + d * 64 + (((kc * 4 + fq) ^ (d & 7)) * 8));
        oacc[nd] = __builtin_amdgcn_mfma_f32_16x16x32_f16(
            __builtin_bit_cast(f16x8, pf), __builtin_bit_cast(f16x8, vf),
            oacc[nd], 0, 0, 0);
      }
    }
    __syncthreads();
  }

#pragma unroll
  for (int j = 0; j < 4; ++j) {
    float l = lrun[j];
#pragma unroll
    for (int o = 1; o < 16; o <<= 1) l += __shfl_xor(l, o);
    const int rg = q0 + w * 16 + fq * 4 + j;
    const float inv = (rg < QL) ? (1.f / l) : 0.f;
#pragma unroll
    for (int nd = 0; nd < 4; ++nd)
      AOb[((size_t)(b * 512 + rg)) * 512 + h * 64 + nd * 16 + fr] =
          f2bf(oacc[nd][j] * inv);
  }
}

// Vt[b][h][d][s] (f16) from V[b*S+s][h*64+d] (bf16)
__global__ __launch_bounds__(256) void build_vt(const ushort_t* __restrict__ V,
                                                ushort_t* __restrict__ Vt) {
  __shared__ ushort_t tile[64 * 65];
  const int s0 = blockIdx.x * 64, h = blockIdx.y, b = blockIdx.z;
  const int t = threadIdx.x;
#pragma unroll
  for (int i = 0; i < 16; ++i) {
    int idx = i * 256 + t;
    int sl = idx >> 6, d = idx & 63;
    tile[sl * 65 + d] = V[(size_t)(b * 512 + s0 + sl) * 512 + h * 64 + d];
  }
  __syncthreads();
  _Float16* vt = (_Float16*)Vt;
#pragma unroll
  for (int i = 0; i < 16; ++i) {
    int idx = i * 256 + t;
    int d = idx >> 6, sl = idx & 63;
    vt[((size_t)(b * 8 + h) * 64 + d) * 512 + (s0 + sl)] =
        (_Float16)bf2f(tile[sl * 65 + d]);
  }
}

// result1 = LN(attn_out(bf16) + queries(f32)) -> bf16
__global__ __launch_bounds__(256) void ln1(const ushort_t* __restrict__ xb,
                                           const float* __restrict__ r,
                                           const float* __restrict__ g,
                                           const float* __restrict__ be,
                                           ushort_t* __restrict__ ob) {
  const int row = blockIdx.x, t = threadIdx.x;
  const size_t base = (size_t)row * 512;
  const uint_t xv = ((const uint_t*)(xb + base))[t];
  const f32x2 rv = ((const f32x2*)(r + base))[t];
  float v0 = bf2f((ushort_t)(xv & 0xffff)) + rv[0];
  float v1 = bf2f((ushort_t)(xv >> 16)) + rv[1];
  float s = v0 + v1, q = v0 * v0 + v1 * v1;
#pragma unroll
  for (int o = 32; o; o >>= 1) { s += __shfl_xor(s, o); q += __shfl_xor(q, o); }
  __shared__ float ps[4], pq[4];
  const int w = t >> 6, lane = t & 63;
  if (lane == 0) { ps[w] = s; pq[w] = q; }
  __syncthreads();
  s = ps[0] + ps[1] + ps[2] + ps[3];
  q = pq[0] + pq[1] + pq[2] + pq[3];
  const float mu = s * 0.001953125f;
  const float var = q * 0.001953125f - mu * mu;
  const float inv = 1.0f / sqrtf(var + 1e-3f);
  const float y0 = (v0 - mu) * inv * g[2 * t] + be[2 * t];
  const float y1 = (v1 - mu) * inv * g[2 * t + 1] + be[2 * t + 1];
  ((uint_t*)(ob + base))[t] = (uint_t)f2bf(y0) | ((uint_t)f2bf(y1) << 16);
}

// result3 = LN(h2 + result1(bf16)) -> bf16  (single FFN2 output, no split-K)
__global__ __launch_bounds__(256) void ln2(const float* __restrict__ h2,
                                           const ushort_t* __restrict__ r1b,
                                           const float* __restrict__ g,
                                           const float* __restrict__ be,
                                           ushort_t* __restrict__ ob) {
  const int row = blockIdx.x, t = threadIdx.x;
  const size_t base = (size_t)row * 512;
  const f32x2 a = ((const f32x2*)(h2 + base))[t];
  const uint_t rv = ((const uint_t*)(r1b + base))[t];
  float v0 = a[0] + bf2f((ushort_t)(rv & 0xffff));
  float v1 = a[1] + bf2f((ushort_t)(rv >> 16));
  float s = v0 + v1, q = v0 * v0 + v1 * v1;
#pragma unroll
  for (int o = 32; o; o >>= 1) { s += __shfl_xor(s, o); q += __shfl_xor(q, o); }
  __shared__ float ps[4], pq[4];
  const int w = t >> 6, lane = t & 63;
  if (lane == 0) { ps[w] = s; pq[w] = q; }
  __syncthreads();
  s = ps[0] + ps[1] + ps[2] + ps[3];
  q = pq[0] + pq[1] + pq[2] + pq[3];
  const float mu = s * 0.001953125f;
  const float var = q * 0.001953125f - mu * mu;
  const float inv = 1.0f / sqrtf(var + 1e-3f);
  const float y0 = (v0 - mu) * inv * g[2 * t] + be[2 * t];
  const float y1 = (v1 - mu) * inv * g[2 * t + 1] + be[2 * t + 1];
  ((uint_t*)(ob + base))[t] = (uint_t)f2bf(y0) | ((uint_t)f2bf(y1) << 16);
}

__global__ void mean_partial(const ushort_t* __restrict__ r3,
                             float* __restrict__ part) {
  const int sc = blockIdx.x, b = blockIdx.y, d = threadIdx.x;
  float s = 0.f;
#pragma unroll 4
  for (int i = 0; i < 64; ++i)
    s += bf2f(r3[(size_t)(b * 512 + sc * 64 + i) * 512 + d]);
  part[(size_t)(b * 8 + sc) * 512 + d] = s;
}
__global__ void mean_final(const float* __restrict__ part, float* __restrict__ out) {
  const int b = blockIdx.x, d = threadIdx.x;
  float s = 0.f;
#pragma unroll
  for (int i = 0; i < 8; ++i) s += part[(size_t)(b * 8 + i) * 512 + d];
  out[b * 512 + d] = s * (1.0f / 512.0f);
}

// ---------------------------------------------------------------------------
extern "C" void kernel_launch(void* const* d_in, const int* in_sizes, int n_in,
                              void* d_out, int out_size, void* d_ws, size_t ws_size,
                              hipStream_t stream) {
  (void)in_sizes; (void)n_in; (void)out_size; (void)ws_size;
  const float* queries = (const float*)d_in[0];
  const float* keys    = (const float*)d_in[1];
  const float* W_Q = (const float*)d_in[2];
  const float* W_K = (const float*)d_in[3];
  const float* W_V = (const float*)d_in[4];
  const float* fw1 = (const float*)d_in[5];
  const float* fw2 = (const float*)d_in[6];
  const float* ln_g = (const float*)d_in[7];
  const float* ln_b = (const float*)d_in[8];
  const int* qlen = (const int*)d_in[9];
  const int* klen = (const int*)d_in[10];
  float* out = (float*)d_out;

  char* ws = (char*)d_ws;
  const size_t MB = 1048576;
  ushort_t* XQ  = (ushort_t*)(ws + 0 * MB);    // 16MB
  ushort_t* XK  = (ushort_t*)(ws + 16 * MB);   // 16MB
  ushort_t* Qb  = (ushort_t*)(ws + 32 * MB);   // 16MB (QKV out, stride 16MB)
  ushort_t* VT  = (ushort_t*)(ws + 80 * MB);   // 16MB
  ushort_t* AOb = (ushort_t*)(ws + 96 * MB);   // 16MB bf16
  ushort_t* R1B = (ushort_t*)(ws + 112 * MB);  // 16MB bf16
  ushort_t* H1  = (ushort_t*)(ws + 0 * MB);    // 64MB alias (XQ..Kb dead post-flash)
  float*    H2  = (float*)(ws + 128 * MB);     // 32MB f32 (single, no split-K)
  ushort_t* R3B = (ushort_t*)(ws + 192 * MB);  // 16MB bf16
  char*     wsw = ws + 208 * MB;
  ushort_t* WQT  = (ushort_t*)(wsw);                       // 0.5MB x3 (adjacent!)
  ushort_t* FW1T = (ushort_t*)(wsw + 3 * 524288);          // 2MB
  ushort_t* FW2T = (ushort_t*)(wsw + 3 * 524288 + 2097152);// 2MB
  float*    PART = (float*)(wsw + 3 * 524288 + 2 * 2097152);

  // 1) fused preprocessing: cvt q/k + all 5 weight transposes
  prep<<<19200, 256, 0, stream>>>(queries, keys, XQ, XK, W_Q, W_K, W_V,
                                  fw1, fw2, WQT, FW1T, FW2T);
  // 2) QKV, 128-row panels + length skip: z=0 XQ@W_Q(x0.125); z=1 XK@W_K; z=2 XK@W_V
  gemm_bt<4><<<dim3(4, 128, 3), 256, 0, stream>>>(
      XQ, XK, 512, WQT, 512, (void*)Qb, 512, 512, 262144, 16 * MB, qlen, klen);
  // 3) V transpose per (b,h) -> f16
  build_vt<<<dim3(8, 8, 32), 256, 0, stream>>>(Qb + 16777216, VT);
  // 4) flash attention -> bf16 (length-aware, 64-row q-tiles)
  flash_attn<<<2048, 256, 0, stream>>>(Qb, Qb + 8388608, VT, AOb, qlen, klen);
  // 5) result1 = LN(attn_out + queries) -> bf16
  ln1<<<16384, 256, 0, stream>>>(AOb, queries, ln_g, ln_b, R1B);
  // 6) FFN1: h1 = relu(result1 @ fw1) bf16
  gemm256<2><<<dim3(8, 64, 1), 512, 0, stream>>>(
      R1B, R1B, 512, FW1T, 512, (void*)H1, 2048, 512, 0, 0);
  // 7) FFN2 single-K (no split): 512 blocks = 2/CU, nk=64 -> H2 f32 32MB
  gemm_bt<0><<<dim3(4, 128, 1), 256, 0, stream>>>(
      H1, H1, 2048, FW2T, 2048, (void*)H2, 512, 2048, 0, 0, qlen, klen);
  // 8) result3 = LN(result1 + h2) -> bf16
  ln2<<<16384, 256, 0, stream>>>(H2, R1B, ln_g, ln_b, R3B);
  // 9) mean over S
  mean_partial<<<dim3(8, 32), 512, 0, stream>>>(R3B, PART);
  mean_final<<<32, 512, 0, stream>>>(PART, out);
}

// Round 13
// 226.987 us; speedup vs baseline: 1.0261x; 1.0261x over previous
//
#include <hip/hip_runtime.h>

typedef unsigned short ushort_t;
typedef unsigned int uint_t;
typedef __attribute__((ext_vector_type(4))) float f32x4;
typedef __attribute__((ext_vector_type(2))) float f32x2;
typedef __attribute__((ext_vector_type(8))) short s16x8;
typedef __attribute__((ext_vector_type(8))) _Float16 f16x8;
typedef __attribute__((ext_vector_type(4))) unsigned short u16x4;

#define NEGV -60000.0f

// Session lessons (R7-R12, keep for future edits):
//  - launch_bounds below accumulator footprint -> scratch spill (R7: 4.4x).
//  - atomic mean-fusion at 32-way contention -> serialization (R8: +29us).
//  - 2-byte scattered epilogue stores (fused V^T) -> write-path bound (R9).
//  - inlining the bf16 cvt into the latency-bound GEMM -> conflicts+VALU on
//    critical path beat the ~15us separate BW-bound pass (R10: -24us).
//  - GEMM inner-schedule plateau: 62-66us across 5 schedules at K=512/1024
//    (2ph-128^2, ring3, 8ph/4ph-256^2, BK=32) - short-K latency-bound.
//  - un-split FFN2 (K=2048 single pass, R12): +4us — per-K-step stall scales
//    with K-depth; split-K=2 via gemm256 is on the efficient frontier.

__device__ __forceinline__ ushort_t f2bf(float f) {
  unsigned int u = __builtin_bit_cast(unsigned int, f);
  return (ushort_t)((u + 0x7fffu + ((u >> 16) & 1u)) >> 16);
}
__device__ __forceinline__ float bf2f(ushort_t h) {
  unsigned int u = ((unsigned int)h) << 16;
  return __builtin_bit_cast(float, u);
}
__device__ __forceinline__ void gload_lds16(const void* g, void* l) {
  __builtin_amdgcn_global_load_lds(
      (const __attribute__((address_space(1))) unsigned int*)g,
      (__attribute__((address_space(3))) unsigned int*)l, 16, 0, 0);
}

// ---------------------------------------------------------------------------
// 128x128 2-phase MFMA GEMM (R2 structure) for QKV with PER-PANEL LENGTH SKIP.
// Skip rules (panel rows [s0,s0+128) of batch b, s0=m0&511):
//  z=0 (Q): skip iff QL<=s0; z=1 (K): skip iff KL<=s0;
//  z=2 (V): skip iff KL<=s0 && KL!=1 (KL==1 -> uniform softmax reads all V).
// ---------------------------------------------------------------------------
template<int EPI>
__global__ __launch_bounds__(256)
void gemm_bt(const ushort_t* __restrict__ A, const ushort_t* __restrict__ A2,
             int lda,
             const ushort_t* __restrict__ Bt, int ldb,
             void* __restrict__ Cv, int ldc, int K,
             long long sB, long long sC,
             const int* __restrict__ qlen, const int* __restrict__ klen)
{
  __shared__ ushort_t As[2][128 * 32];
  __shared__ ushort_t Bs[2][128 * 32];

  const int tid = threadIdx.x;
  const int w = tid >> 6;
  const int lane = tid & 63;
  const int z = blockIdx.z;

  const ushort_t* Az = (z == 0) ? A : A2;
  const ushort_t* Bz = Bt + (size_t)z * sB;

  const int orig = blockIdx.x + gridDim.x * blockIdx.y;
  const int bx = (orig >> 3) % gridDim.x;
  const int by = (orig & 7) + 8 * ((orig >> 3) / gridDim.x);
  const int m0 = by * 128;
  const int n0 = bx * 128;

  if constexpr (EPI == 4) {
    const int s0 = m0 & 511;
    if (s0) {
      const int b = m0 >> 9;
      const int L = (z == 0) ? qlen[b] : klen[b];
      if (L <= s0 && !(z == 2 && L == 1)) return;  // panel never read downstream
    }
  }

  const int wm = (w >> 1) * 64;
  const int wn = (w & 1) * 64;

  f32x4 acc[4][4];
#pragma unroll
  for (int m = 0; m < 4; ++m)
#pragma unroll
    for (int n = 0; n < 4; ++n)
      acc[m][n] = (f32x4){0.f, 0.f, 0.f, 0.f};

  const int cA0 = w * 64 + lane;   // 16B chunk id: row*4 + kc
  const int cA1 = 256 + cA0;
  const int rA0 = cA0 >> 2, kO0 = (cA0 & 3) * 8;
  const int rA1 = cA1 >> 2, kO1 = (cA1 & 3) * 8;

  auto stage = [&](int p, int k0) {
    gload_lds16(Az + (size_t)(m0 + rA0) * lda + (k0 + kO0),
                As[p] + (size_t)(w * 64) * 8);
    gload_lds16(Az + (size_t)(m0 + rA1) * lda + (k0 + kO1),
                As[p] + (size_t)(256 + w * 64) * 8);
    gload_lds16(Bz + (size_t)(n0 + rA0) * ldb + (k0 + kO0),
                Bs[p] + (size_t)(w * 64) * 8);
    gload_lds16(Bz + (size_t)(n0 + rA1) * ldb + (k0 + kO1),
                Bs[p] + (size_t)(256 + w * 64) * 8);
  };

  const int nk = K >> 5;
  stage(0, 0);
  __syncthreads();
  for (int kt = 0; kt < nk; ++kt) {
    const int p = kt & 1;
    if (kt + 1 < nk) stage(p ^ 1, (kt + 1) << 5);  // prefetch next tile

    s16x8 af[4], bfr[4];
#pragma unroll
    for (int m = 0; m < 4; ++m)
      af[m] = *(const s16x8*)(As[p] + (size_t)(wm + m * 16 + (lane & 15)) * 32 +
                              ((lane >> 4) * 8));
#pragma unroll
    for (int n = 0; n < 4; ++n)
      bfr[n] = *(const s16x8*)(Bs[p] + (size_t)(wn + n * 16 + (lane & 15)) * 32 +
                               ((lane >> 4) * 8));
#pragma unroll
    for (int m = 0; m < 4; ++m)
#pragma unroll
      for (int n = 0; n < 4; ++n)
        acc[m][n] = __builtin_amdgcn_mfma_f32_16x16x32_bf16(af[m], bfr[n],
                                                            acc[m][n], 0, 0, 0);
    __syncthreads();
  }

  const float s0v = (EPI == 4 && z == 0) ? 0.125f : 1.0f;
  char* Cz = (char*)Cv + (size_t)sC * z;
  const int r_base = (lane >> 4) * 4;
  const int c_base = lane & 15;
#pragma unroll
  for (int m = 0; m < 4; ++m)
#pragma unroll
    for (int n = 0; n < 4; ++n)
#pragma unroll
      for (int j = 0; j < 4; ++j) {
        const int rg = m0 + wm + m * 16 + r_base + j;
        const int cg = n0 + wn + n * 16 + c_base;
        float v = acc[m][n][j];
        const size_t idx = (size_t)rg * ldc + cg;
        if constexpr (EPI == 0) {
          ((float*)Cz)[idx] = v;
        } else if constexpr (EPI == 2) {
          ((ushort_t*)Cz)[idx] = f2bf(fmaxf(v, 0.f));
        } else {
          ((ushort_t*)Cz)[idx] = f2bf(v * s0v);
        }
      }
}

// ---------------------------------------------------------------------------
// 256x256 4-phase MFMA GEMM (BK=64, 128KB LDS, (512,2)) — FFN1 / FFN2.
// ---------------------------------------------------------------------------
template<int EPI>
__global__ __launch_bounds__(512, 2)
void gemm256(const ushort_t* __restrict__ A, const ushort_t* __restrict__ A2,
             int lda,
             const ushort_t* __restrict__ Bt, int ldb,
             void* __restrict__ Cv, int ldc, int K,
             long long sB, long long sC)
{
  __shared__ ushort_t Asm[2][16384];   // [buf][256 rows x 64 cols]
  __shared__ ushort_t Bsm[2][16384];

  const int tid = threadIdx.x, wid = tid >> 6, lane = tid & 63;
  const int wr = wid >> 2, wc = wid & 3;       // 2 x 4 wave grid
  const int fr = lane & 15, fq = lane >> 4;
  const int z = blockIdx.z;

  const ushort_t* Az = (z == 0) ? A : A2;
  const ushort_t* Bz = Bt + (size_t)z * sB;

  const int orig = blockIdx.x + gridDim.x * blockIdx.y;
  const int bx = (orig >> 3) % gridDim.x;
  const int by = (orig & 7) + 8 * ((orig >> 3) / gridDim.x);
  const int m0 = by * 256, n0 = bx * 256;

  const int rr0 = tid >> 3;                          // 0..63 (second is +64)
  const int ks = (((tid & 7) ^ (rr0 & 7)) * 8);      // (rr+64)&7 == rr&7

  auto stageA = [&](int p, int kt, int h) {
    const ushort_t* s = Az + (size_t)(m0 + h * 128 + rr0) * lda + kt * 64 + ks;
    ushort_t* d = &Asm[p][h * 8192 + tid * 8];
    gload_lds16(s, d);
    gload_lds16(s + (size_t)64 * lda, d + 4096);
  };
  auto stageB = [&](int p, int kt, int h) {
    const ushort_t* s = Bz + (size_t)(n0 + h * 128 + rr0) * ldb + kt * 64 + ks;
    ushort_t* d = &Bsm[p][h * 8192 + tid * 8];
    gload_lds16(s, d);
    gload_lds16(s + (size_t)64 * ldb, d + 4096);
  };
  auto ldA = [&](int p, int mi, int kc) -> s16x8 {
    const int R = wr * 128 + mi * 16 + fr;
    return *(const s16x8*)(&Asm[p][R * 64 + (((kc * 4 + fq) ^ (fr & 7)) * 8)]);
  };
  auto ldB = [&](int p, int ni, int kc) -> s16x8 {
    const int R = wc * 64 + ni * 16 + fr;
    return *(const s16x8*)(&Bsm[p][R * 64 + (((kc * 4 + fq) ^ (fr & 7)) * 8)]);
  };

  f32x4 acc[8][4];
#pragma unroll
  for (int m = 0; m < 8; ++m)
#pragma unroll
    for (int n = 0; n < 4; ++n)
      acc[m][n] = (f32x4){0.f, 0.f, 0.f, 0.f};

  const int nk = K >> 6;
  const int niter = nk >> 1;

  stageB(0, 0, 0); stageB(0, 0, 1);
  stageA(0, 0, 0); stageA(0, 0, 1);
  stageA(1, 1, 0); stageA(1, 1, 1);
  stageB(1, 1, 0); stageB(1, 1, 1);
  asm volatile("s_waitcnt vmcnt(8)" ::: "memory");   // tile0 landed
  __builtin_amdgcn_s_barrier();

  s16x8 af[4][2], bf[4][2];

  for (int it = 0; it < niter; ++it) {
    const int T = 2 * it;
    const bool more = (it + 1 < niter);

    // ---- phase A: tile T (buf0), acc rows 0-3 ----
#pragma unroll
    for (int mi = 0; mi < 4; ++mi)
#pragma unroll
      for (int kc = 0; kc < 2; ++kc) af[mi][kc] = ldA(0, mi, kc);
#pragma unroll
    for (int ni = 0; ni < 4; ++ni)
#pragma unroll
      for (int kc = 0; kc < 2; ++kc) bf[ni][kc] = ldB(0, ni, kc);
    if (it) { stageA(1, T + 1, 0); stageA(1, T + 1, 1); }
    __builtin_amdgcn_s_barrier();
    asm volatile("s_waitcnt lgkmcnt(0)" ::: "memory");
    __builtin_amdgcn_s_setprio(1);
#pragma unroll
    for (int mi = 0; mi < 4; ++mi)
#pragma unroll
      for (int ni = 0; ni < 4; ++ni)
#pragma unroll
        for (int kc = 0; kc < 2; ++kc)
          acc[mi][ni] = __builtin_amdgcn_mfma_f32_16x16x32_bf16(
              af[mi][kc], bf[ni][kc], acc[mi][ni], 0, 0, 0);
    __builtin_amdgcn_s_setprio(0);
    __builtin_amdgcn_s_barrier();

    // ---- phase B: tile T, acc rows 4-7 ----
#pragma unroll
    for (int mi = 0; mi < 4; ++mi)
#pragma unroll
      for (int kc = 0; kc < 2; ++kc) af[mi][kc] = ldA(0, 4 + mi, kc);
    if (more) {
      stageB(0, T + 2, 0); stageB(0, T + 2, 1);
      asm volatile("s_waitcnt vmcnt(4)" ::: "memory");  // tile T+1 landed
    } else {
      asm volatile("s_waitcnt vmcnt(0)" ::: "memory");
    }
    __builtin_amdgcn_s_barrier();
    asm volatile("s_waitcnt lgkmcnt(0)" ::: "memory");
    __builtin_amdgcn_s_setprio(1);
#pragma unroll
    for (int mi = 0; mi < 4; ++mi)
#pragma unroll
      for (int ni = 0; ni < 4; ++ni)
#pragma unroll
        for (int kc = 0; kc < 2; ++kc)
          acc[4 + mi][ni] = __builtin_amdgcn_mfma_f32_16x16x32_bf16(
              af[mi][kc], bf[ni][kc], acc[4 + mi][ni], 0, 0, 0);
    __builtin_amdgcn_s_setprio(0);
    __builtin_amdgcn_s_barrier();

    // ---- phase C: tile T+1 (buf1), acc rows 0-3 ----
#pragma unroll
    for (int mi = 0; mi < 4; ++mi)
#pragma unroll
      for (int kc = 0; kc < 2; ++kc) af[mi][kc] = ldA(1, mi, kc);
#pragma unroll
    for (int ni = 0; ni < 4; ++ni)
#pragma unroll
      for (int kc = 0; kc < 2; ++kc) bf[ni][kc] = ldB(1, ni, kc);
    if (more) { stageA(0, T + 2, 0); stageA(0, T + 2, 1); }
    __builtin_amdgcn_s_barrier();
    asm volatile("s_waitcnt lgkmcnt(0)" ::: "memory");
    __builtin_amdgcn_s_setprio(1);
#pragma unroll
    for (int mi = 0; mi < 4; ++mi)
#pragma unroll
      for (int ni = 0; ni < 4; ++ni)
#pragma unroll
        for (int kc = 0; kc < 2; ++kc)
          acc[mi][ni] = __builtin_amdgcn_mfma_f32_16x16x32_bf16(
              af[mi][kc], bf[ni][kc], acc[mi][ni], 0, 0, 0);
    __builtin_amdgcn_s_setprio(0);
    __builtin_amdgcn_s_barrier();

    // ---- phase D: tile T+1, acc rows 4-7 ----
#pragma unroll
    for (int mi = 0; mi < 4; ++mi)
#pragma unroll
      for (int kc = 0; kc < 2; ++kc) af[mi][kc] = ldA(1, 4 + mi, kc);
    if (more) {
      stageB(1, T + 3, 0); stageB(1, T + 3, 1);
      asm volatile("s_waitcnt vmcnt(4)" ::: "memory");  // tile T+2 landed
    } else {
      asm volatile("s_waitcnt vmcnt(0)" ::: "memory");
    }
    __builtin_amdgcn_s_barrier();
    asm volatile("s_waitcnt lgkmcnt(0)" ::: "memory");
    __builtin_amdgcn_s_setprio(1);
#pragma unroll
    for (int mi = 0; mi < 4; ++mi)
#pragma unroll
      for (int ni = 0; ni < 4; ++ni)
#pragma unroll
        for (int kc = 0; kc < 2; ++kc)
          acc[4 + mi][ni] = __builtin_amdgcn_mfma_f32_16x16x32_bf16(
              af[mi][kc], bf[ni][kc], acc[4 + mi][ni], 0, 0, 0);
    __builtin_amdgcn_s_setprio(0);
    __builtin_amdgcn_s_barrier();
  }

  // epilogue
  const float s0 = (EPI == 4 && z == 0) ? 0.125f : 1.0f;
  char* Cz = (char*)Cv + (size_t)sC * z;
  const int rb = fq * 4;
#pragma unroll
  for (int mi = 0; mi < 8; ++mi)
#pragma unroll
    for (int ni = 0; ni < 4; ++ni)
#pragma unroll
      for (int j = 0; j < 4; ++j) {
        const int rg = m0 + wr * 128 + mi * 16 + rb + j;
        const int cg = n0 + wc * 64 + ni * 16 + fr;
        float v = acc[mi][ni][j];
        const size_t idx = (size_t)rg * ldc + cg;
        if constexpr (EPI == 0) {
          ((float*)Cz)[idx] = v;
        } else if constexpr (EPI == 2) {
          ((ushort_t*)Cz)[idx] = f2bf(fmaxf(v, 0.f));
        } else {
          ((ushort_t*)Cz)[idx] = f2bf(v * s0);
        }
      }
}

// ---------------------------------------------------------------------------
// Fused preprocessing: one dispatch replaces 2x cvt_bf16 + 5x transpose_cvt.
// ---------------------------------------------------------------------------
__global__ __launch_bounds__(256)
void prep(const float* __restrict__ q, const float* __restrict__ k,
          ushort_t* __restrict__ XQ, ushort_t* __restrict__ XK,
          const float* __restrict__ W_Q, const float* __restrict__ W_K,
          const float* __restrict__ W_V,
          const float* __restrict__ fw1, const float* __restrict__ fw2,
          ushort_t* __restrict__ WQT, ushort_t* __restrict__ FW1T,
          ushort_t* __restrict__ FW2T)
{
  __shared__ float tile[32][33];
  int bid = blockIdx.x;
  if (bid < 16384) {
    const float* in = (bid < 8192) ? q : k;
    ushort_t* outp = (bid < 8192) ? XQ : XK;
    int i = (bid & 8191) * 256 + threadIdx.x;
    f32x4 v = ((const f32x4*)in)[i];
    u16x4 o;
#pragma unroll
    for (int j = 0; j < 4; ++j) o[j] = f2bf(v[j]);
    ((u16x4*)outp)[i] = o;
    return;
  }
  bid -= 16384;
  const float* in;
  ushort_t* outp;
  int R, C, bx, by;
  if (bid < 768) {
    int zz = bid >> 8, idx = bid & 255;
    in = (zz == 0) ? W_Q : (zz == 1) ? W_K : W_V;
    outp = WQT + zz * 262144;
    R = 512; C = 512; bx = idx & 15; by = idx >> 4;
  } else if (bid < 1792) {
    int idx = bid - 768;
    in = fw1; outp = FW1T; R = 512; C = 2048; bx = idx & 63; by = idx >> 6;
  } else {
    int idx = bid - 1792;
    in = fw2; outp = FW2T; R = 2048; C = 512; bx = idx & 15; by = idx >> 4;
  }
  const int c0 = bx * 32, r0 = by * 32;
  const int tx = threadIdx.x & 31, ty = threadIdx.x >> 5;
#pragma unroll
  for (int i = 0; i < 32; i += 8)
    tile[ty + i][tx] = in[(size_t)(r0 + ty + i) * C + (c0 + tx)];
  __syncthreads();
#pragma unroll
  for (int i = 0; i < 32; i += 8)
    outp[(size_t)(c0 + ty + i) * R + (r0 + tx)] = f2bf(tile[tx][ty + i]);
}

// ---------------------------------------------------------------------------
// Flash attention: block = (b, h, 64-q-tile); 4 waves x 16 q-rows.
// ---------------------------------------------------------------------------
__global__ __launch_bounds__(256, 4)
void flash_attn(const ushort_t* __restrict__ Qg, const ushort_t* __restrict__ Kg,
                const ushort_t* __restrict__ Vt, ushort_t* __restrict__ AOb,
                const int* __restrict__ qlen, const int* __restrict__ klen)
{
  __shared__ ushort_t sm[20480];  // buf0(8K K + 8K V B) | buf1 | PQ(8KB)
  ushort_t* PQ = sm + 16384;

  const int tid = threadIdx.x, w = tid >> 6, lane = tid & 63;
  const int fr = lane & 15, fq = lane >> 4;

  int id = blockIdx.x;
  id = (id & 7) * 256 + (id >> 3);           // XCD swizzle (2048 blocks)
  const int qt = id & 7, h = (id >> 3) & 7, b = id >> 6;
  const int q0 = qt * 64;
  const int KL = klen[b], QL = qlen[b];

  if (q0 >= QL) {
#pragma unroll
    for (int i = 0; i < 4; ++i) {
      int idx = i * 256 + tid;
      int rr = idx >> 4, cc = (idx & 15) << 2;
      *(u16x4*)&AOb[((size_t)(b * 512 + q0 + rr)) * 512 + h * 64 + cc] =
          (u16x4){0, 0, 0, 0};
    }
    return;
  }

  int nt = (KL + 63) >> 6;                   // KV tiles actually needed
  if (KL == 1) nt = 8;                       // degenerate: uniform over 512

  const ushort_t* Qrow = Qg + ((size_t)(b * 512 + q0)) * 512 + h * 64;
  const ushort_t* Krow = Kg + ((size_t)b * 512) * 512 + h * 64;
  const ushort_t* Vrow = Vt + (((size_t)b * 8 + h) * 64) * 512;

#pragma unroll
  for (int i = 0; i < 2; ++i) {
    int s = i * 256 + tid, r = s >> 3, c = (s & 7) ^ (r & 7);
    gload_lds16(Qrow + (size_t)r * 512 + c * 8, PQ + (i * 256 + w * 64) * 8);
  }
#pragma unroll
  for (int i = 0; i < 2; ++i) {
    int s = i * 256 + tid, r = s >> 3, c = (s & 7) ^ (r & 7);
    gload_lds16(Krow + (size_t)r * 512 + c * 8, sm + (i * 256 + w * 64) * 8);
    gload_lds16(Vrow + (size_t)r * 512 + c * 8, sm + 4096 + (i * 256 + w * 64) * 8);
  }
  __syncthreads();

  s16x8 qf[2];
#pragma unroll
  for (int kc = 0; kc < 2; ++kc) {
    int r = w * 16 + fr;
    qf[kc] = *(const s16x8*)(PQ + r * 64 + (((kc * 4 + fq) ^ (r & 7)) * 8));
  }

  float mrun[4], lrun[4];
  f32x4 oacc[4];
#pragma unroll
  for (int j = 0; j < 4; ++j) { mrun[j] = -1e30f; lrun[j] = 0.f; }
#pragma unroll
  for (int nd = 0; nd < 4; ++nd) oacc[nd] = (f32x4){0.f, 0.f, 0.f, 0.f};

  for (int t = 0; t < nt; ++t) {
    ushort_t* Kb = sm + (t & 1) * 8192;
    ushort_t* Vb = Kb + 4096;
    if (t + 1 < nt) {
      const int kv1 = (t + 1) * 64;
      ushort_t* Kn = sm + ((t + 1) & 1) * 8192;
#pragma unroll
      for (int i = 0; i < 2; ++i) {
        int s = i * 256 + tid, r = s >> 3, c = (s & 7) ^ (r & 7);
        gload_lds16(Krow + (size_t)(kv1 + r) * 512 + c * 8,
                    Kn + (i * 256 + w * 64) * 8);
        gload_lds16(Vrow + (size_t)r * 512 + kv1 + c * 8,
                    Kn + 4096 + (i * 256 + w * 64) * 8);
      }
    }
    const int kv0 = t * 64;

    f32x4 sacc[4];
#pragma unroll
    for (int n = 0; n < 4; ++n) sacc[n] = (f32x4){0.f, 0.f, 0.f, 0.f};
#pragma unroll
    for (int n = 0; n < 4; ++n)
#pragma unroll
      for (int kc = 0; kc < 2; ++kc) {
        int r = n * 16 + fr;
        s16x8 kf = *(const s16x8*)(Kb + r * 64 + (((kc * 4 + fq) ^ (r & 7)) * 8));
        sacc[n] = __builtin_amdgcn_mfma_f32_16x16x32_bf16(qf[kc], kf, sacc[n], 0, 0, 0);
      }

#pragma unroll
    for (int j = 0; j < 4; ++j) {
      const int rl = w * 16 + fq * 4 + j;
      const int rg = q0 + rl;
      float sv[4];
      float tmax = -1e30f;
#pragma unroll
      for (int n = 0; n < 4; ++n) {
        int cg = kv0 + n * 16 + fr;
        float v = sacc[n][j];
        if (cg >= KL || cg == rg) v = NEGV;
        sv[n] = v;
        tmax = fmaxf(tmax, v);
      }
#pragma unroll
      for (int o = 1; o < 16; o <<= 1) tmax = fmaxf(tmax, __shfl_xor(tmax, o));
      const float mnew = fmaxf(mrun[j], tmax);
      const float sf = __expf(mrun[j] - mnew);
      mrun[j] = mnew;
      float ps = 0.f;
      _Float16* prow = (_Float16*)(PQ + rl * 64);
#pragma unroll
      for (int n = 0; n < 4; ++n) {
        float p = __expf(sv[n] - mnew);
        ps += p;
        int cl = n * 2 + (fr >> 3);
        prow[((cl ^ (rl & 7)) * 8) + (fr & 7)] = (_Float16)p;
      }
      lrun[j] = lrun[j] * sf + ps;
#pragma unroll
      for (int nd = 0; nd < 4; ++nd) oacc[nd][j] *= sf;
    }

#pragma unroll
    for (int kc = 0; kc < 2; ++kc) {
      const int rl = w * 16 + fr;
      s16x8 pf = *(const s16x8*)(PQ + rl * 64 + (((kc * 4 + fq) ^ (rl & 7)) * 8));
#pragma unroll
      for (int nd = 0; nd < 4; ++nd) {
        int d = nd * 16 + fr;
        s16x8 vf = *(const s16x8*)(Vb + d * 64 + (((kc * 4 + fq) ^ (d & 7)) * 8));
        oacc[nd] = __builtin_amdgcn_mfma_f32_16x16x32_f16(
            __builtin_bit_cast(f16x8, pf), __builtin_bit_cast(f16x8, vf),
            oacc[nd], 0, 0, 0);
      }
    }
    __syncthreads();
  }

#pragma unroll
  for (int j = 0; j < 4; ++j) {
    float l = lrun[j];
#pragma unroll
    for (int o = 1; o < 16; o <<= 1) l += __shfl_xor(l, o);
    const int rg = q0 + w * 16 + fq * 4 + j;
    const float inv = (rg < QL) ? (1.f / l) : 0.f;
#pragma unroll
    for (int nd = 0; nd < 4; ++nd)
      AOb[((size_t)(b * 512 + rg)) * 512 + h * 64 + nd * 16 + fr] =
          f2bf(oacc[nd][j] * inv);
  }
}

// Vt[b][h][d][s] (f16) from V[b*S+s][h*64+d] (bf16)
__global__ __launch_bounds__(256) void build_vt(const ushort_t* __restrict__ V,
                                                ushort_t* __restrict__ Vt) {
  __shared__ ushort_t tile[64 * 65];
  const int s0 = blockIdx.x * 64, h = blockIdx.y, b = blockIdx.z;
  const int t = threadIdx.x;
#pragma unroll
  for (int i = 0; i < 16; ++i) {
    int idx = i * 256 + t;
    int sl = idx >> 6, d = idx & 63;
    tile[sl * 65 + d] = V[(size_t)(b * 512 + s0 + sl) * 512 + h * 64 + d];
  }
  __syncthreads();
  _Float16* vt = (_Float16*)Vt;
#pragma unroll
  for (int i = 0; i < 16; ++i) {
    int idx = i * 256 + t;
    int d = idx >> 6, sl = idx & 63;
    vt[((size_t)(b * 8 + h) * 64 + d) * 512 + (s0 + sl)] =
        (_Float16)bf2f(tile[sl * 65 + d]);
  }
}

// result1 = LN(attn_out(bf16) + queries(f32)) -> bf16
__global__ __launch_bounds__(256) void ln1(const ushort_t* __restrict__ xb,
                                           const float* __restrict__ r,
                                           const float* __restrict__ g,
                                           const float* __restrict__ be,
                                           ushort_t* __restrict__ ob) {
  const int row = blockIdx.x, t = threadIdx.x;
  const size_t base = (size_t)row * 512;
  const uint_t xv = ((const uint_t*)(xb + base))[t];
  const f32x2 rv = ((const f32x2*)(r + base))[t];
  float v0 = bf2f((ushort_t)(xv & 0xffff)) + rv[0];
  float v1 = bf2f((ushort_t)(xv >> 16)) + rv[1];
  float s = v0 + v1, q = v0 * v0 + v1 * v1;
#pragma unroll
  for (int o = 32; o; o >>= 1) { s += __shfl_xor(s, o); q += __shfl_xor(q, o); }
  __shared__ float ps[4], pq[4];
  const int w = t >> 6, lane = t & 63;
  if (lane == 0) { ps[w] = s; pq[w] = q; }
  __syncthreads();
  s = ps[0] + ps[1] + ps[2] + ps[3];
  q = pq[0] + pq[1] + pq[2] + pq[3];
  const float mu = s * 0.001953125f;
  const float var = q * 0.001953125f - mu * mu;
  const float inv = 1.0f / sqrtf(var + 1e-3f);
  const float y0 = (v0 - mu) * inv * g[2 * t] + be[2 * t];
  const float y1 = (v1 - mu) * inv * g[2 * t + 1] + be[2 * t + 1];
  ((uint_t*)(ob + base))[t] = (uint_t)f2bf(y0) | ((uint_t)f2bf(y1) << 16);
}

// result3 = LN(h2a + h2b + result1(bf16)) -> bf16
__global__ __launch_bounds__(256) void ln2(const float* __restrict__ h2a,
                                           const float* __restrict__ h2b,
                                           const ushort_t* __restrict__ r1b,
                                           const float* __restrict__ g,
                                           const float* __restrict__ be,
                                           ushort_t* __restrict__ ob) {
  const int row = blockIdx.x, t = threadIdx.x;
  const size_t base = (size_t)row * 512;
  const f32x2 a = ((const f32x2*)(h2a + base))[t];
  const f32x2 b = ((const f32x2*)(h2b + base))[t];
  const uint_t rv = ((const uint_t*)(r1b + base))[t];
  float v0 = a[0] + b[0] + bf2f((ushort_t)(rv & 0xffff));
  float v1 = a[1] + b[1] + bf2f((ushort_t)(rv >> 16));
  float s = v0 + v1, q = v0 * v0 + v1 * v1;
#pragma unroll
  for (int o = 32; o; o >>= 1) { s += __shfl_xor(s, o); q += __shfl_xor(q, o); }
  __shared__ float ps[4], pq[4];
  const int w = t >> 6, lane = t & 63;
  if (lane == 0) { ps[w] = s; pq[w] = q; }
  __syncthreads();
  s = ps[0] + ps[1] + ps[2] + ps[3];
  q = pq[0] + pq[1] + pq[2] + pq[3];
  const float mu = s * 0.001953125f;
  const float var = q * 0.001953125f - mu * mu;
  const float inv = 1.0f / sqrtf(var + 1e-3f);
  const float y0 = (v0 - mu) * inv * g[2 * t] + be[2 * t];
  const float y1 = (v1 - mu) * inv * g[2 * t + 1] + be[2 * t + 1];
  ((uint_t*)(ob + base))[t] = (uint_t)f2bf(y0) | ((uint_t)f2bf(y1) << 16);
}

__global__ void mean_partial(const ushort_t* __restrict__ r3,
                             float* __restrict__ part) {
  const int sc = blockIdx.x, b = blockIdx.y, d = threadIdx.x;
  float s = 0.f;
#pragma unroll 4
  for (int i = 0; i < 64; ++i)
    s += bf2f(r3[(size_t)(b * 512 + sc * 64 + i) * 512 + d]);
  part[(size_t)(b * 8 + sc) * 512 + d] = s;
}
__global__ void mean_final(const float* __restrict__ part, float* __restrict__ out) {
  const int b = blockIdx.x, d = threadIdx.x;
  float s = 0.f;
#pragma unroll
  for (int i = 0; i < 8; ++i) s += part[(size_t)(b * 8 + i) * 512 + d];
  out[b * 512 + d] = s * (1.0f / 512.0f);
}

// ---------------------------------------------------------------------------
extern "C" void kernel_launch(void* const* d_in, const int* in_sizes, int n_in,
                              void* d_out, int out_size, void* d_ws, size_t ws_size,
                              hipStream_t stream) {
  (void)in_sizes; (void)n_in; (void)out_size; (void)ws_size;
  const float* queries = (const float*)d_in[0];
  const float* keys    = (const float*)d_in[1];
  const float* W_Q = (const float*)d_in[2];
  const float* W_K = (const float*)d_in[3];
  const float* W_V = (const float*)d_in[4];
  const float* fw1 = (const float*)d_in[5];
  const float* fw2 = (const float*)d_in[6];
  const float* ln_g = (const float*)d_in[7];
  const float* ln_b = (const float*)d_in[8];
  const int* qlen = (const int*)d_in[9];
  const int* klen = (const int*)d_in[10];
  float* out = (float*)d_out;

  char* ws = (char*)d_ws;
  const size_t MB = 1048576;
  ushort_t* XQ  = (ushort_t*)(ws + 0 * MB);    // 16MB
  ushort_t* XK  = (ushort_t*)(ws + 16 * MB);   // 16MB
  ushort_t* Qb  = (ushort_t*)(ws + 32 * MB);   // 16MB (QKV out, stride 16MB)
  ushort_t* VT  = (ushort_t*)(ws + 80 * MB);   // 16MB
  ushort_t* AOb = (ushort_t*)(ws + 96 * MB);   // 16MB bf16
  ushort_t* R1B = (ushort_t*)(ws + 112 * MB);  // 16MB bf16
  ushort_t* H1  = (ushort_t*)(ws + 0 * MB);    // 64MB alias (XQ..Kb dead post-flash)
  float*    H2  = (float*)(ws + 128 * MB);     // 64MB (two 32MB split-K halves)
  ushort_t* R3B = (ushort_t*)(ws + 192 * MB);  // 16MB bf16
  char*     wsw = ws + 208 * MB;
  ushort_t* WQT  = (ushort_t*)(wsw);                       // 0.5MB x3 (adjacent!)
  ushort_t* FW1T = (ushort_t*)(wsw + 3 * 524288);          // 2MB
  ushort_t* FW2T = (ushort_t*)(wsw + 3 * 524288 + 2097152);// 2MB
  float*    PART = (float*)(wsw + 3 * 524288 + 2 * 2097152);

  // 1) fused preprocessing: cvt q/k + all 5 weight transposes
  prep<<<19200, 256, 0, stream>>>(queries, keys, XQ, XK, W_Q, W_K, W_V,
                                  fw1, fw2, WQT, FW1T, FW2T);
  // 2) QKV, 128-row panels + length skip: z=0 XQ@W_Q(x0.125); z=1 XK@W_K; z=2 XK@W_V
  gemm_bt<4><<<dim3(4, 128, 3), 256, 0, stream>>>(
      XQ, XK, 512, WQT, 512, (void*)Qb, 512, 512, 262144, 16 * MB, qlen, klen);
  // 3) V transpose per (b,h) -> f16
  build_vt<<<dim3(8, 8, 32), 256, 0, stream>>>(Qb + 16777216, VT);
  // 4) flash attention -> bf16 (length-aware, 64-row q-tiles)
  flash_attn<<<2048, 256, 0, stream>>>(Qb, Qb + 8388608, VT, AOb, qlen, klen);
  // 5) result1 = LN(attn_out + queries) -> bf16
  ln1<<<16384, 256, 0, stream>>>(AOb, queries, ln_g, ln_b, R1B);
  // 6) FFN1: h1 = relu(result1 @ fw1) bf16
  gemm256<2><<<dim3(8, 64, 1), 512, 0, stream>>>(
      R1B, R1B, 512, FW1T, 512, (void*)H1, 2048, 512, 0, 0);
  // 7) FFN2 split-K=2: z in {0,1} over K-halves -> H2a/H2b f32
  gemm256<0><<<dim3(2, 64, 2), 512, 0, stream>>>(
      H1, H1 + 1024, 2048, FW2T, 2048, (void*)H2, 512, 1024, 1024, 32 * MB);
  // 8) result3 = LN(result1 + h2a + h2b) -> bf16
  ln2<<<16384, 256, 0, stream>>>(H2, H2 + 8388608, R1B, ln_g, ln_b, R3B);
  // 9) mean over S
  mean_partial<<<dim3(8, 32), 512, 0, stream>>>(R3B, PART);
  mean_final<<<32, 512, 0, stream>>>(PART, out);
}